// Round 6
// baseline (193.388 us; speedup 1.0000x reference)
//
#include <hip/hip_runtime.h>
#include <hip/hip_bf16.h>
#include <float.h>

// Problem constants
#define N_ROWS 32768          // 32 * 1024 query vectors
#define DIMS   64
#define K_EMB  8192
#define NT     (K_EMB / 16)   // 512 column tiles of 16
#define NQ     8              // K split into 8 slices
#define NTQ    (NT / NQ)      // 64 tiles per slice (6 bits -> planted in mantissa)
#define RG     4              // row-groups (16 rows each) per wave -> 64 rows/wave
#define KEYMASK 0xFFFFFFC0u   // clear 6 low mantissa bits; plant within-slice tile idx
// err budget: split-bf16 mfma ~6.5e-4 + 2x key-mask (~5e-4 at |v|<=64) -> 3.5e-3
#define GAP_THR 3.5e-3f

typedef __attribute__((ext_vector_type(8))) short s8v;   // 8 bf16 (A/B frag)
typedef __attribute__((ext_vector_type(4))) float f4v;   // C/D frag
typedef __attribute__((ext_vector_type(4))) int   i4v;   // 16B load unit

// Workspace layout (bytes) — total ~5.8 MB
#define WS_EFRAG 0                              // 2 MiB
#define WS_EN2   (2 * 1024 * 1024)              // 8192 f32: -0.5*||e||^2
#define WS_IDX   (WS_EN2 + K_EMB * 4)           // 32768 i32 (merged idx)
#define WS_KEY   (WS_IDX + N_ROWS * 4)          // 32768 u64 fixup keys
#define WS_BH    (WS_KEY + N_ROWS * 8)          // [NQ][N] best key per slice (then nb)
#define WS_SH    (WS_BH + NQ * N_ROWS * 4)      // [NQ][N] second key
#define WS_CH    (WS_SH + NQ * N_ROWS * 4)      // [NQ][N] col idx
#define WS_CTL   (WS_CH + NQ * N_ROWS * 4)      // {double loss; int wl_count; int done}
#define WS_WL    (WS_CTL + 16)                  // worklist

// Output layout (float32 elements): [quantized | loss | indices]
#define OUT_LOSS (N_ROWS * DIMS)
#define OUT_IDX  (N_ROWS * DIMS + 1)

__device__ inline short bfh(float v) {
    __hip_bfloat16 h = __float2bfloat16(v);
    return __builtin_bit_cast(short, h);
}
__device__ inline float bff(short s) {
    __hip_bfloat16 h = __builtin_bit_cast(__hip_bfloat16, s);
    return __bfloat162float(h);
}

// ---------------------------------------------------------------------------
// Prep: embeddings -> MFMA B-frag layout (hi/lo bf16 split) + fused -||e||^2/2.
// B-frag: lane holds B[k=(lane>>4)*8+j][n=lane&15]. Frags: 0=hi k[0,32),
// 1=hi k[32,64), 2=lo k[0,32), 3=lo k[32,64). [tile][frag][lane][16B].
// 256 blocks x 128 threads (R5 used 128 blocks = half the CUs idle).
// Also zeroes the CTL block (loss acc + wl_count + done) — replaces a memset.
// ---------------------------------------------------------------------------
__global__ void vq_prep(const float* __restrict__ emb, short* __restrict__ efrag,
                        float* __restrict__ en2, int4* __restrict__ ctl) {
    if (blockIdx.x == 0 && threadIdx.x == 0) *ctl = make_int4(0, 0, 0, 0);
    int gid = blockIdx.x * 128 + threadIdx.x;   // NT*64 = 32768 threads
    int t = gid >> 6, lane = gid & 63;
    int m = lane & 15, q = lane >> 4;
    const float* er = emb + (size_t)(t * 16 + m) * DIMS;
    s8v hi0, lo0, hi1, lo1;
    float ss = 0.f;
#pragma unroll
    for (int j = 0; j < 8; ++j) {
        float v0 = er[q * 8 + j];
        float v1 = er[32 + q * 8 + j];
        ss += v0 * v0 + v1 * v1;
        short h0 = bfh(v0); lo0[j] = bfh(v0 - bff(h0)); hi0[j] = h0;
        short h1 = bfh(v1); lo1[j] = bfh(v1 - bff(h1)); hi1[j] = h1;
    }
    s8v* base = (s8v*)efrag + (size_t)t * 4 * 64;
    base[0 * 64 + lane] = hi0;
    base[1 * 64 + lane] = hi1;
    base[2 * 64 + lane] = lo0;
    base[3 * 64 + lane] = lo1;
    // reduce sum of squares across the 4 q-lanes sharing m
    ss += __shfl_xor(ss, 16, 64);
    ss += __shfl_xor(ss, 32, 64);
    if (q == 0) en2[t * 16 + m] = -0.5f * ss;
}

// ---------------------------------------------------------------------------
// Phase 1: barrier-free per-wave MFMA distance + per-K-slice argmax/second.
// Grid (512, 8) x 64 threads: one WAVE per (64-row group, K-slice). No LDS,
// no __syncthreads: B-frags stream global->VGPR from the XCD L2 (efrag 2MB
// fits; total re-read 1GB ~= 2.3TB/s per XCD, 54% of L2 ceiling) through a
// 2-deep NAMED double buffer (runtime-indexed arrays would hit scratch).
// Rationale: R2/R4/R5 all pinned at MfmaUtil ~39 / VALUBusy ~52 / dur ~2.2x
// the 50us MFMA floor regardless of occupancy or ops/value — the barrier'd
// global_load_lds structure drains vmcnt(0)+lgkmcnt(0) at every syncthreads.
// Per-wave register pipelines have no barriers; hw tracks per-wave vmcnt.
// Bookkeeping: mantissa-planted keys, 3 VALU/value (and_or+fmed3+fmax); any
// mis-ordering from the <=2^-17 perturbation is < GAP_THR -> exact fixup.
// waves_per_eu(2,3): VGPR cap 170 >= ~150 natural (R1/R3 lesson: never cap
// below need); 3 waves/SIMD + 4 independent RG chains feed the MFMA pipe.
// ---------------------------------------------------------------------------
#define LOADT(B0, B1, B2, B3, CC, T) do {                 \
    const i4v* _p = bsrc + (size_t)(T) * 256;             \
    B0 = _p[lane];       B1 = _p[64 + lane];              \
    B2 = _p[128 + lane]; B3 = _p[192 + lane];             \
    CC = ep[(T) * 16];                                    \
} while (0)

#define COMPT(B0, B1, B2, B3, CC, CODE) do {                                     \
    f4v cinit = {CC, CC, CC, CC};   /* C init = -||e_col||^2 / 2 */              \
    _Pragma("unroll")                                                            \
    for (int g = 0; g < RG; ++g) {                                               \
        f4v acc;                                                                 \
        acc = __builtin_amdgcn_mfma_f32_16x16x32_bf16(ahi[g][0], __builtin_bit_cast(s8v, B0), cinit, 0, 0, 0); \
        acc = __builtin_amdgcn_mfma_f32_16x16x32_bf16(ahi[g][1], __builtin_bit_cast(s8v, B1), acc, 0, 0, 0);   \
        acc = __builtin_amdgcn_mfma_f32_16x16x32_bf16(ahi[g][0], __builtin_bit_cast(s8v, B2), acc, 0, 0, 0);   \
        acc = __builtin_amdgcn_mfma_f32_16x16x32_bf16(ahi[g][1], __builtin_bit_cast(s8v, B3), acc, 0, 0, 0);   \
        acc = __builtin_amdgcn_mfma_f32_16x16x32_bf16(alo[g][0], __builtin_bit_cast(s8v, B0), acc, 0, 0, 0);   \
        acc = __builtin_amdgcn_mfma_f32_16x16x32_bf16(alo[g][1], __builtin_bit_cast(s8v, B1), acc, 0, 0, 0);   \
        _Pragma("unroll")                                                        \
        for (int r = 0; r < 4; ++r) {   /* C/D: col=lane&15, row=quad*4+r */     \
            float kf = __uint_as_float(                                          \
                (__float_as_uint(acc[r]) & KEYMASK) | (unsigned)(CODE));         \
            sec[g][r]  = __builtin_amdgcn_fmed3f(kf, sec[g][r], best[g][r]);     \
            best[g][r] = fmaxf(best[g][r], kf);                                  \
        }                                                                        \
    }                                                                            \
} while (0)

__global__ __launch_bounds__(64)
__attribute__((amdgpu_waves_per_eu(2, 3))) void vq_phase1(
    const float* __restrict__ x, const short* __restrict__ efrag,
    const float* __restrict__ en2,
    float* __restrict__ bh, float* __restrict__ sh, int* __restrict__ ch) {
    int lane = threadIdx.x;
    int m = lane & 15, q = lane >> 4;
    int kh = blockIdx.y;
    int row0 = blockIdx.x * 64;

    // A-frags for RG row-groups: A[m][k=quad*8+j], hi/lo, two K-halves of dims.
    s8v ahi[RG][2], alo[RG][2];
#pragma unroll
    for (int g = 0; g < RG; ++g) {
        const float* xr = x + (size_t)(row0 + g * 16 + m) * DIMS + q * 8;
#pragma unroll
        for (int j = 0; j < 8; ++j) {
            float v0 = xr[j], v1 = xr[32 + j];
            short h0 = bfh(v0); alo[g][0][j] = bfh(v0 - bff(h0)); ahi[g][0][j] = h0;
            short h1 = bfh(v1); alo[g][1][j] = bfh(v1 - bff(h1)); ahi[g][1][j] = h1;
        }
    }

    float best[RG][4], sec[RG][4];
#pragma unroll
    for (int g = 0; g < RG; ++g)
#pragma unroll
        for (int r = 0; r < 4; ++r) { best[g][r] = -FLT_MAX; sec[g][r] = -FLT_MAX; }

    const i4v*   bsrc = (const i4v*)efrag + (size_t)kh * NTQ * 256;
    const float* ep   = en2 + (size_t)kh * NTQ * 16 + m;

    // 2-deep register pipeline over the slice's 64 tiles (no barriers).
    i4v A0, A1, A2, A3, B0, B1, B2, B3;
    float cA, cB;
    LOADT(A0, A1, A2, A3, cA, 0);
#pragma unroll 1
    for (int t = 0; t < NTQ; t += 2) {
        LOADT(B0, B1, B2, B3, cB, t + 1);        // NTQ even: always valid
        COMPT(A0, A1, A2, A3, cA, t);
        if (t + 2 < NTQ) LOADT(A0, A1, A2, A3, cA, t + 2);
        COMPT(B0, B1, B2, B3, cB, t + 1);
    }

    // Reduce (best, second) keys across the 16 col-lanes of each quad.
    // Winner lane identified by bit-equality ballot; it reconstructs the col.
#pragma unroll
    for (int g = 0; g < RG; ++g)
#pragma unroll
    for (int r = 0; r < 4; ++r) {
        float b = best[g][r], sv = sec[g][r];
#pragma unroll
        for (int off = 1; off < 16; off <<= 1) {
            float ob = __shfl_xor(b, off, 64);
            float os = __shfl_xor(sv, off, 64);
            sv = fmaxf(fminf(b, ob), fmaxf(sv, os));
            b  = fmaxf(b, ob);
        }
        unsigned long long bal =
            __ballot(__float_as_uint(best[g][r]) == __float_as_uint(b));
        int win = __ffsll(bal >> (q * 16)) - 1;   // lowest matching m in our group
        if (m == win) {
            int tl  = (int)(__float_as_uint(b) & 63u);
            int col = ((kh * NTQ + tl) << 4) | m;
            int o = kh * N_ROWS + row0 + g * 16 + q * 4 + r;
            bh[o] = b; sh[o] = sv; ch[o] = col;
        }
    }
}

// ---------------------------------------------------------------------------
// Merge the NQ K-slices per row; store merged best key (for fixup prefilter);
// zero fixup keys; build worklist.
// ---------------------------------------------------------------------------
__global__ void vq_merge(const float* __restrict__ bh, const float* __restrict__ sh,
                         const int* __restrict__ ch, int* __restrict__ idx_buf,
                         unsigned long long* __restrict__ key8,
                         float* __restrict__ nbv,
                         int* __restrict__ wl, int* __restrict__ wl_count) {
    int row = blockIdx.x * 256 + threadIdx.x;
    float nb = bh[row];
    int   c  = ch[row];
    float ns = -FLT_MAX;
#pragma unroll
    for (int h = 1; h < NQ; ++h) {
        float b = bh[h * N_ROWS + row];
        int   cc = ch[h * N_ROWS + row];
        if (b > nb) { ns = nb; nb = b; c = cc; }
        else        { ns = fmaxf(ns, b); }
    }
#pragma unroll
    for (int h = 0; h < NQ; ++h) ns = fmaxf(ns, sh[h * N_ROWS + row]);
    idx_buf[row] = c;
    key8[row] = 0ULL;
    nbv[row] = nb;
    if (nb - ns < GAP_THR) {
        int pos = atomicAdd(wl_count, 1);
        wl[pos] = row;
    }
}

// ---------------------------------------------------------------------------
// Fixup: exact fp32 rescan. One wave per 64-column chunk; each lane owns one
// embedding column kept entirely in registers (16 float4), looping over the
// worklist rows (x row loads are wave-uniform). Candidates merged via
// atomicMax on packed (sortable(f) << 32 | ~idx) — exact argmax, ties->low
// idx. Prefilter: local max must be within GAP_THR of the merged approx best
// (exact winner always passes: |approx_key - exact| <= ~1.2e-3 < GAP_THR).
// Early-exit BEFORE the 16KB e-preload when this block's row-slice is empty.
// ---------------------------------------------------------------------------
__global__ __launch_bounds__(64) void vq_fixup(
    const float* __restrict__ x, const float* __restrict__ emb,
    const float* __restrict__ en2, const float* __restrict__ nbv,
    unsigned long long* __restrict__ key8,
    const int* __restrict__ wl, const int* __restrict__ wl_count) {
    int lane = threadIdx.x;                 // 64 threads = 1 wave
    int cchunk = blockIdx.x & 127;          // 128 col-chunks of 64
    int rslice = blockIdx.x >> 7;           // 16 row slices
    int cnt = *wl_count;
    if (rslice >= cnt) return;              // empty slice: skip e-preload
    int c = cchunk * 64 + lane;
    const float4* er = (const float4*)(emb + (size_t)c * DIMS);
    float4 e[16];
#pragma unroll
    for (int qq = 0; qq < 16; ++qq) e[qq] = er[qq];
    float c0 = en2[c];
    for (int wi = rslice; wi < cnt; wi += 16) {
        int row = wl[wi];
        const float4* xr = (const float4*)(x + (size_t)row * DIMS);
        float d = 0.f;
#pragma unroll
        for (int qq = 0; qq < 16; ++qq) {
            float4 ee = e[qq];
            float4 xx = xr[qq];
            d += ee.x * xx.x + ee.y * xx.y + ee.z * xx.z + ee.w * xx.w;
        }
        float bf_ = d + c0;
        int bc_ = c;
#pragma unroll
        for (int off = 1; off < 64; off <<= 1) {
            float of = __shfl_xor(bf_, off, 64);
            int   oc = __shfl_xor(bc_, off, 64);
            if (of > bf_ || (of == bf_ && oc < bc_)) { bf_ = of; bc_ = oc; }
        }
        if (lane == 0 && bf_ >= nbv[row] - GAP_THR) {
            unsigned int u = __float_as_uint(bf_);
            unsigned int sb = ((int)u < 0) ? ~u : (u | 0x80000000u);
            unsigned long long key = ((unsigned long long)sb << 32) | (unsigned int)(~bc_);
            atomicMax(&key8[row], key);
        }
    }
}

// ---------------------------------------------------------------------------
// Gather quantized rows, accumulate squared error, emit indices as floats.
// Last block (device-scope completion counter) also writes the final loss.
// ---------------------------------------------------------------------------
__global__ void vq_gather(const float* __restrict__ x, const float* __restrict__ emb,
                          const int* __restrict__ idx_buf,
                          const unsigned long long* __restrict__ key8,
                          float* __restrict__ out, double* __restrict__ loss_acc,
                          int* __restrict__ done_count) {
    int row = blockIdx.x * blockDim.x + threadIdx.x;
    unsigned long long k = key8[row];
    int idx = k ? (int)(~(unsigned int)k) : idx_buf[row];
    const float4* ev = (const float4*)(emb + (size_t)idx * DIMS);
    const float4* xv = (const float4*)(x + (size_t)row * DIMS);
    float4* ov = (float4*)(out + (size_t)row * DIMS);
    float s = 0.f;
#pragma unroll
    for (int qq = 0; qq < 16; ++qq) {
        float4 ee = ev[qq];
        float4 xx = xv[qq];
        float dx = ee.x - xx.x, dy = ee.y - xx.y, dz = ee.z - xx.z, dw = ee.w - xx.w;
        s += dx * dx + dy * dy + dz * dz + dw * dw;
        ov[qq] = ee;
    }
#pragma unroll
    for (int off = 32; off > 0; off >>= 1) s += __shfl_down(s, off, 64);
    if ((threadIdx.x & 63) == 0) atomicAdd(loss_acc, (double)s);
    out[OUT_IDX + row] = (float)idx;
    __syncthreads();                        // all 4 wave-atomics of this block issued
    if (threadIdx.x == 0) {
        __threadfence();                    // order our adds before the counter inc
        int d = atomicAdd(done_count, 1);
        if (d == (int)gridDim.x - 1) {
            double total = atomicAdd(loss_acc, 0.0);   // coherent read of final sum
            out[OUT_LOSS] = (float)(1.25 * total / (double)(N_ROWS * DIMS));
        }
    }
}

// ---------------------------------------------------------------------------
extern "C" void kernel_launch(void* const* d_in, const int* in_sizes, int n_in,
                              void* d_out, int out_size, void* d_ws, size_t ws_size,
                              hipStream_t stream) {
    const float* x   = (const float*)d_in[0];
    const float* emb = (const float*)d_in[1];
    float* out = (float*)d_out;
    char*  ws  = (char*)d_ws;

    short* efrag   = (short*)(ws + WS_EFRAG);
    float* en2     = (float*)(ws + WS_EN2);
    int*   idx_buf = (int*)(ws + WS_IDX);
    unsigned long long* key8 = (unsigned long long*)(ws + WS_KEY);
    float* bhb     = (float*)(ws + WS_BH);
    float* shb     = (float*)(ws + WS_SH);
    int*   chb     = (int*)(ws + WS_CH);
    double* loss_acc = (double*)(ws + WS_CTL);
    int*   wl_count  = (int*)(ws + WS_CTL + 8);
    int*   done_cnt  = (int*)(ws + WS_CTL + 12);
    int*   wl        = (int*)(ws + WS_WL);

    vq_prep<<<(NT * 64) / 128, 128, 0, stream>>>(emb, efrag, en2, (int4*)(ws + WS_CTL));  // 256 blocks
    vq_phase1<<<dim3(N_ROWS / 64, NQ), 64, 0, stream>>>(x, efrag, en2, bhb, shb, chb);    // 4096 waves
    vq_merge<<<N_ROWS / 256, 256, 0, stream>>>(bhb, shb, chb, idx_buf, key8, bhb, wl, wl_count);
    vq_fixup<<<2048, 64, 0, stream>>>(x, emb, en2, bhb, key8, wl, wl_count);
    vq_gather<<<N_ROWS / 256, 256, 0, stream>>>(x, emb, idx_buf, key8, out, loss_acc, done_cnt);
}